// Round 7
// baseline (256.232 us; speedup 1.0000x reference)
//
#include <hip/hip_runtime.h>
#include <cstdint>

typedef unsigned short u16;
typedef unsigned int   u32;
typedef __attribute__((ext_vector_type(8))) short  short8;
typedef __attribute__((ext_vector_type(4))) float  floatx4;

#define NPTS 524288   // B*N2*K

__device__ __forceinline__ float b2f(u16 h) { return __uint_as_float(((u32)h) << 16); }
__device__ __forceinline__ u16 f2b(float f) {
  u32 u = __float_as_uint(f);
  return (u16)((u + 0x7FFFu + ((u >> 16) & 1u)) >> 16);
}
__device__ __forceinline__ u32 pk_bf16(float lo, float hi) {
  return (u32)f2b(lo) | ((u32)f2b(hi) << 16);
}
__device__ __forceinline__ short8 u4s8(uint4 q) {
  union { uint4 q; short8 s; } x; x.q = q; return x.s;
}

// BN + ReLU on 8 packed bf16 -> bf16 MFMA fragment half
__device__ __forceinline__ short8 bn_relu_frag(uint4 a, const float* sc, const float* sh) {
  u32 w[4] = { a.x, a.y, a.z, a.w };
  union { u32 u[4]; short8 s; } r;
  #pragma unroll
  for (int i = 0; i < 4; ++i) {
    float lo = fmaxf(b2f((u16)(w[i] & 0xffffu)) * sc[2 * i]     + sh[2 * i],     0.f);
    float hi = fmaxf(b2f((u16)(w[i] >> 16))     * sc[2 * i + 1] + sh[2 * i + 1], 0.f);
    r.u[i] = pk_bf16(lo, hi);
  }
  return r.s;
}

// ---- combined prep: featT transpose + xyzT transpose + W->bf16 ----
// Wb layout (u16): W0 64x96 @0 (cols 67..95 zero) ; W1 64x64 @6144 ; W2 128x64 @10240
__global__ __launch_bounds__(256) void prep_all(const float* __restrict__ inf,
                                                const float* __restrict__ ixyz,
                                                const float* __restrict__ W0,
                                                const float* __restrict__ W1,
                                                const float* __restrict__ W2,
                                                u16* __restrict__ featT,
                                                float4* __restrict__ xyzT,
                                                u16* __restrict__ Wb) {
  __shared__ float tile[32 * 33];
  const int bk = blockIdx.x, t = threadIdx.x;
  if (bk < 4096) {          // in_feature [b][c][n] f32 -> featT [b][n][c] bf16
    int b = bk >> 8, rem = bk & 255, cc = rem >> 7, nc = rem & 127;
    #pragma unroll
    for (int i = 0; i < 4; ++i) {
      int flat = t + i * 256;
      int cl = flat >> 5, nl = flat & 31;
      tile[cl * 33 + nl] = inf[(size_t)((b * 64) + cc * 32 + cl) * 4096 + nc * 32 + nl];
    }
    __syncthreads();
    #pragma unroll
    for (int i = 0; i < 4; ++i) {
      int flat = t + i * 256;
      int nl = flat >> 5, cl = flat & 31;
      featT[(size_t)((b << 12) + nc * 32 + nl) * 64 + cc * 32 + cl] = f2b(tile[cl * 33 + nl]);
    }
  } else if (bk < 4352) {   // in_xyz [b][3][n] -> xyzT [b][n][float4]
    int g = (bk - 4096) * 256 + t;
    int b = g >> 12, n = g & 4095;
    const float* p = ixyz + (size_t)b * 12288;
    xyzT[g] = make_float4(p[n], p[4096 + n], p[8192 + n], 0.f);
  } else {                  // weights: 18432 u16 over 72 blocks
    int s = (bk - 4352) * 256 + t;
    u16 v = 0;
    if (s < 6144)       { int o = s / 96, c = s % 96; if (c < 67) v = f2b(W0[o * 67 + c]); }
    else if (s < 10240) { int q = s - 6144;  int o = q >> 6, c = q & 63; v = f2b(W1[o * 64 + c]); }
    else                { int q = s - 10240; int o = q >> 6, c = q & 63; v = f2b(W2[o * 64 + c]); }
    Wb[s] = v;
  }
}

// ---- L0/L1: 256 rows/block, A direct global->regs, per-sub pacing barrier ----
template<bool GATHER>
__global__ __launch_bounds__(256, 4) void gemm64(
    const u16* __restrict__ xsrc, const float4* __restrict__ xyzT,
    const float* __restrict__ oxyz, const int* __restrict__ nbr,
    const u16* __restrict__ Wb, const float* __restrict__ ssin,
    u16* __restrict__ yout, float* __restrict__ partial) {
  constexpr int KC = GATHER ? 96 : 64;
  __shared__ float redA[256], redB[256];

  const int t = threadIdx.x, blk = blockIdx.x;
  const int lane = t & 63, wv = t >> 6, lr = lane & 15, quad = lane >> 4;
  const int P0 = blk * 256;
  const int b = blk >> 7;

  // W fragments -> registers
  short8 wf[4][GATHER ? 3 : 2];
  #pragma unroll
  for (int nt = 0; nt < 4; ++nt) {
    const u16* wr = Wb + (nt * 16 + lr) * KC + quad * 8;
    #pragma unroll
    for (int ks = 0; ks < (GATHER ? 3 : 2); ++ks)
      wf[nt][ks] = u4s8(*(const uint4*)(wr + ks * 32));
  }

  // BN scale/shift for this lane's input channels
  float sc[16], sh[16];
  if constexpr (!GATHER) {
    #pragma unroll
    for (int ks = 0; ks < 2; ++ks) {
      const float* ps = ssin + ks * 32 + quad * 8;
      #pragma unroll
      for (int j = 0; j < 8; ++j) {
        sc[ks * 8 + j] = ps[j];
        sh[ks * 8 + j] = ps[64 + j];
      }
    }
  }

  int idx4[4];
  if constexpr (GATHER) {
    #pragma unroll
    for (int sub = 0; sub < 4; ++sub) idx4[sub] = nbr[P0 + sub * 64 + wv * 16 + lr];
  }

  uint4 A0[2], A1[2];
  float DX[2] = {0.f, 0.f}, DY[2] = {0.f, 0.f}, DZ[2] = {0.f, 0.f};

  auto load_sub = [&](int sub, int bu) {
    if constexpr (GATHER) {
      const int id = idx4[sub];
      const u16* row = xsrc + ((size_t)((b << 12) + id)) * 64;
      A0[bu] = *(const uint4*)(row + quad * 8);
      A1[bu] = *(const uint4*)(row + quad * 8 + 32);
      if (quad == 0) {
        float4 p = xyzT[(b << 12) + id];
        const int n2 = ((P0 + sub * 64 + wv * 16) >> 5) & 1023;
        DX[bu] = p.x - oxyz[(b * 3 + 0) * 1024 + n2];
        DY[bu] = p.y - oxyz[(b * 3 + 1) * 1024 + n2];
        DZ[bu] = p.z - oxyz[(b * 3 + 2) * 1024 + n2];
      }
    } else {
      const u16* row = xsrc + ((size_t)(P0 + sub * 64 + wv * 16 + lr)) * 64;
      A0[bu] = *(const uint4*)(row + quad * 8);
      A1[bu] = *(const uint4*)(row + quad * 8 + 32);
    }
  };

  load_sub(0, 0);

  float s1[4] = {0.f, 0.f, 0.f, 0.f}, s2[4] = {0.f, 0.f, 0.f, 0.f};
  u32* yo = (u32*)yout;

  #pragma unroll
  for (int sub = 0; sub < 4; ++sub) {
    const int cur = sub & 1, nxt = cur ^ 1;
    if (sub < 3) load_sub(sub + 1, nxt);

    short8 av0, av1, av2;
    if constexpr (GATHER) {
      av0 = u4s8(A0[cur]);
      av1 = u4s8(A1[cur]);
      short8 z = {0, 0, 0, 0, 0, 0, 0, 0};
      av2 = z;
      if (quad == 0) {
        av2[0] = (short)f2b(DX[cur]);
        av2[1] = (short)f2b(DY[cur]);
        av2[2] = (short)f2b(DZ[cur]);
      }
    } else {
      av0 = bn_relu_frag(A0[cur], sc + 0, sh + 0);
      av1 = bn_relu_frag(A1[cur], sc + 8, sh + 8);
    }

    floatx4 acc[4];
    #pragma unroll
    for (int nt = 0; nt < 4; ++nt) acc[nt] = (floatx4){0.f, 0.f, 0.f, 0.f};
    #pragma unroll
    for (int nt = 0; nt < 4; ++nt)
      acc[nt] = __builtin_amdgcn_mfma_f32_16x16x32_bf16(av0, wf[nt][0], acc[nt], 0, 0, 0);
    #pragma unroll
    for (int nt = 0; nt < 4; ++nt)
      acc[nt] = __builtin_amdgcn_mfma_f32_16x16x32_bf16(av1, wf[nt][1], acc[nt], 0, 0, 0);
    if constexpr (GATHER) {
      #pragma unroll
      for (int nt = 0; nt < 4; ++nt)
        acc[nt] = __builtin_amdgcn_mfma_f32_16x16x32_bf16(av2, wf[nt][2], acc[nt], 0, 0, 0);
    }

    const int R0 = P0 + sub * 64 + wv * 16 + quad * 4;
    #pragma unroll
    for (int nt = 0; nt < 4; ++nt) {
      #pragma unroll
      for (int r = 0; r < 4; ++r) {
        float v = acc[nt][r];
        s1[nt] += v; s2[nt] += v * v;
        float vo = __shfl_xor(v, 1);
        if ((lr & 1) == 0)
          yo[(size_t)(R0 + r) * 32 + nt * 8 + (lr >> 1)] = pk_bf16(v, vo);
      }
    }
    __syncthreads();   // pacing: keep all waves in the same 32-KB window
  }

  // block stats: shuffle over quads, LDS over waves, single barrier
  #pragma unroll
  for (int nt = 0; nt < 4; ++nt) {
    s1[nt] += __shfl_xor(s1[nt], 16); s1[nt] += __shfl_xor(s1[nt], 32);
    s2[nt] += __shfl_xor(s2[nt], 16); s2[nt] += __shfl_xor(s2[nt], 32);
  }
  if (lane < 16) {
    #pragma unroll
    for (int nt = 0; nt < 4; ++nt) {
      redA[wv * 64 + nt * 16 + lr] = s1[nt];
      redB[wv * 64 + nt * 16 + lr] = s2[nt];
    }
  }
  __syncthreads();
  if (t < 64) {
    partial[(size_t)blk * 128 + t] = redA[t] + redA[64 + t] + redA[128 + t] + redA[192 + t];
  } else if (t < 128) {
    int c = t - 64;
    partial[(size_t)blk * 128 + t] = redB[c] + redB[64 + c] + redB[128 + c] + redB[192 + c];
  }
}

// ---- L2: 256 rows/block; wave = 32 rows (rg) x 64 chans (cg); packed bf16 max/min out ----
__global__ __launch_bounds__(256, 3) void gemm_max(
    const u16* __restrict__ xsrc, const u16* __restrict__ Wb,
    const float* __restrict__ ssin, u32* __restrict__ gm,
    float* __restrict__ partial) {
  __shared__ float redA[256], redB[256];

  const int t = threadIdx.x, blk = blockIdx.x;
  const int lane = t & 63, wv = t >> 6, lr = lane & 15, quad = lane >> 4;
  const int rg = wv >> 1, cg = wv & 1;
  const int P0 = blk * 256;

  short8 wf[4][2];
  #pragma unroll
  for (int nt = 0; nt < 4; ++nt) {
    const u16* wr = Wb + (cg * 64 + nt * 16 + lr) * 64 + quad * 8;
    #pragma unroll
    for (int ks = 0; ks < 2; ++ks) wf[nt][ks] = u4s8(*(const uint4*)(wr + ks * 32));
  }

  float sc[16], sh[16];
  #pragma unroll
  for (int ks = 0; ks < 2; ++ks) {
    const float* ps = ssin + ks * 32 + quad * 8;
    #pragma unroll
    for (int j = 0; j < 8; ++j) {
      sc[ks * 8 + j] = ps[j];
      sh[ks * 8 + j] = ps[64 + j];
    }
  }

  uint4 A[2][4];   // [buf][h*2+ks]
  auto load_sub = [&](int sub, int bu) {
    #pragma unroll
    for (int h = 0; h < 2; ++h) {
      const u16* row = xsrc + ((size_t)(P0 + sub * 64 + rg * 32 + h * 16 + lr)) * 64;
      A[bu][h * 2 + 0] = *(const uint4*)(row + quad * 8);
      A[bu][h * 2 + 1] = *(const uint4*)(row + quad * 8 + 32);
    }
  };
  load_sub(0, 0);

  float s1[4] = {0.f, 0.f, 0.f, 0.f}, s2[4] = {0.f, 0.f, 0.f, 0.f};

  #pragma unroll
  for (int sub = 0; sub < 4; ++sub) {
    const int cur = sub & 1, nxt = cur ^ 1;
    if (sub < 3) load_sub(sub + 1, nxt);

    short8 av[2][2];
    #pragma unroll
    for (int h = 0; h < 2; ++h) {
      av[h][0] = bn_relu_frag(A[cur][h * 2 + 0], sc + 0, sh + 0);
      av[h][1] = bn_relu_frag(A[cur][h * 2 + 1], sc + 8, sh + 8);
    }

    floatx4 acc[2][4];
    #pragma unroll
    for (int h = 0; h < 2; ++h)
      #pragma unroll
      for (int nt = 0; nt < 4; ++nt) acc[h][nt] = (floatx4){0.f, 0.f, 0.f, 0.f};
    #pragma unroll
    for (int ks = 0; ks < 2; ++ks)
      #pragma unroll
      for (int nt = 0; nt < 4; ++nt)
        #pragma unroll
        for (int h = 0; h < 2; ++h)
          acc[h][nt] = __builtin_amdgcn_mfma_f32_16x16x32_bf16(av[h][ks], wf[nt][ks], acc[h][nt], 0, 0, 0);

    float mx[4], mn[4];
    #pragma unroll
    for (int nt = 0; nt < 4; ++nt) {
      mx[nt] = -INFINITY; mn[nt] = INFINITY;
      #pragma unroll
      for (int h = 0; h < 2; ++h)
        #pragma unroll
        for (int r = 0; r < 4; ++r) {
          float v = acc[h][nt][r];
          s1[nt] += v; s2[nt] += v * v;
          mx[nt] = fmaxf(mx[nt], v); mn[nt] = fminf(mn[nt], v);
        }
      mx[nt] = fmaxf(mx[nt], __shfl_xor(mx[nt], 16));
      mx[nt] = fmaxf(mx[nt], __shfl_xor(mx[nt], 32));
      mn[nt] = fminf(mn[nt], __shfl_xor(mn[nt], 16));
      mn[nt] = fminf(mn[nt], __shfl_xor(mn[nt], 32));
    }
    if (lane < 16) {
      const int grp = blk * 8 + sub * 2 + rg;   // b*1024 + n2
      #pragma unroll
      for (int nt = 0; nt < 4; ++nt)
        gm[(size_t)grp * 128 + cg * 64 + nt * 16 + lr] = pk_bf16(mx[nt], mn[nt]);
    }
    __syncthreads();   // pacing: cg-pair re-reads hit L2
  }

  #pragma unroll
  for (int nt = 0; nt < 4; ++nt) {
    s1[nt] += __shfl_xor(s1[nt], 16); s1[nt] += __shfl_xor(s1[nt], 32);
    s2[nt] += __shfl_xor(s2[nt], 16); s2[nt] += __shfl_xor(s2[nt], 32);
  }
  if (lane < 16) {
    #pragma unroll
    for (int nt = 0; nt < 4; ++nt) {
      redA[wv * 64 + nt * 16 + lr] = s1[nt];
      redB[wv * 64 + nt * 16 + lr] = s2[nt];
    }
  }
  __syncthreads();
  if (t < 128) {
    int half = t >> 6, i = t & 63;
    partial[(size_t)blk * 256 + t] = redA[half * 64 + i] + redA[(half + 2) * 64 + i];
  } else {
    int c = t - 128, half = c >> 6, i = c & 63;
    partial[(size_t)blk * 256 + t] = redB[half * 64 + i] + redB[(half + 2) * 64 + i];
  }
}

// ---- stats tree: 2048 x cols -> 64 x cols -> scale/shift ----
__global__ __launch_bounds__(256) void reduce1(const float* __restrict__ partial,
                                               float* __restrict__ tmp, int cols) {
  int c = threadIdx.x;
  if (c >= cols) return;
  int r0 = blockIdx.x * 32;
  float s = 0.f;
  for (int r = 0; r < 32; ++r) s += partial[(size_t)(r0 + r) * cols + c];
  tmp[blockIdx.x * cols + c] = s;
}

__global__ __launch_bounds__(256) void finalize2(const float* __restrict__ tmp,
                                                 const float* __restrict__ gam,
                                                 const float* __restrict__ bet,
                                                 float* __restrict__ ssout, int och) {
  __shared__ float l[256];
  int t = threadIdx.x, cols = 2 * och;
  if (t < cols) {
    float s = 0.f;
    for (int r = 0; r < 64; ++r) s += tmp[r * cols + t];
    l[t] = s;
  }
  __syncthreads();
  if (t < och) {
    const float invN = 1.f / (float)NPTS;
    float mean = l[t] * invN;
    float var  = fmaxf(l[och + t] * invN - mean * mean, 0.f);
    float scale = gam[t] * rsqrtf(var + 1e-5f);
    ssout[t] = scale;
    ssout[och + t] = bet[t] - mean * scale;
  }
}

// ---- final: BN2 + relu on packed max/min, transpose to [b][c][n2] ----
__global__ __launch_bounds__(256) void final_out(const u32* __restrict__ gm,
                                                 const float* __restrict__ ss2,
                                                 float* __restrict__ out) {
  __shared__ float tile[64 * 33];
  int blk = blockIdx.x;                 // 1024 = 16 * 4 * 16
  int b = blk >> 6, rem = blk & 63, cc = rem >> 4, nn = rem & 15;
  int t = threadIdx.x;
  #pragma unroll
  for (int i = 0; i < 8; ++i) {
    int flat = t + i * 256;             // 2048
    int n2l = flat >> 5, cl = flat & 31;
    int c = cc * 32 + cl;
    size_t idx = (size_t)((b << 10) + nn * 64 + n2l) * 128 + c;
    u32 p = gm[idx];
    float mx = b2f((u16)(p & 0xffffu)), mn = b2f((u16)(p >> 16));
    float scv = ss2[c], shv = ss2[128 + c];
    float v = (scv >= 0.f) ? mx : mn;
    tile[n2l * 33 + cl] = fmaxf(scv * v + shv, 0.f);
  }
  __syncthreads();
  #pragma unroll
  for (int i = 0; i < 8; ++i) {
    int flat = t + i * 256;
    int cl = flat >> 6, n2l = flat & 63;
    out[(size_t)((b * 128) + cc * 32 + cl) * 1024 + nn * 64 + n2l] = tile[n2l * 33 + cl];
  }
}

extern "C" void kernel_launch(void* const* d_in, const int* in_sizes, int n_in,
                              void* d_out, int out_size, void* d_ws, size_t ws_size,
                              hipStream_t stream) {
  const float* in_xyz  = (const float*)d_in[0];
  const float* out_xyz = (const float*)d_in[1];
  const float* in_feat = (const float*)d_in[2];
  const int*   nbr     = (const int*)d_in[3];
  const float* W0 = (const float*)d_in[4];
  const float* g0 = (const float*)d_in[5];
  const float* b0 = (const float*)d_in[6];
  const float* W1 = (const float*)d_in[7];
  const float* g1 = (const float*)d_in[8];
  const float* b1 = (const float*)d_in[9];
  const float* W2 = (const float*)d_in[10];
  const float* g2 = (const float*)d_in[11];
  const float* b2 = (const float*)d_in[12];
  float* out = (float*)d_out;

  char* ws = (char*)d_ws;
  float*  ssbuf = (float*)(ws + 0);            // 768 f32
  u16*    Wb    = (u16*)(ws + 4096);           // 18432 u16
  float*  tmpA  = (float*)(ws + 65536);        // 64*256 f32
  u16*    featT = (u16*)(ws + 262144);         // 8 MiB
  float4* xyzT  = (float4*)(ws + 8650752);     // 1 MiB
  u16*    y0    = (u16*)(ws + 9699328);        // 64 MiB
  u16*    y1    = (u16*)(ws + 76808192);       // 64 MiB (end 143,917,056)
  // aliased into dead regions:
  float*  p0    = (float*)(ws + 76808192);     // y1 area; consumed before y1 written
  float*  p1    = (float*)(ws + 262144);       // featT area; featT dead after L0
  u32*    gm    = (u32*)(ws + 9699328);        // y0 area; y0 dead after L1 (8 MiB, packed bf16 mx|mn)
  float*  p2    = (float*)(ws + 9699328 + 8388608);          // 2 MiB

  hipLaunchKernelGGL(prep_all, dim3(4424), dim3(256), 0, stream,
                     in_feat, in_xyz, W0, W1, W2, featT, xyzT, Wb);

  hipLaunchKernelGGL((gemm64<true>), dim3(2048), dim3(256), 0, stream,
                     featT, xyzT, out_xyz, nbr, Wb, nullptr, y0, p0);
  hipLaunchKernelGGL(reduce1, dim3(64), dim3(256), 0, stream, p0, tmpA, 128);
  hipLaunchKernelGGL(finalize2, dim3(1), dim3(256), 0, stream, tmpA, g0, b0, ssbuf, 64);

  hipLaunchKernelGGL((gemm64<false>), dim3(2048), dim3(256), 0, stream,
                     y0, nullptr, nullptr, nullptr, Wb + 6144, ssbuf, y1, p1);
  hipLaunchKernelGGL(reduce1, dim3(64), dim3(256), 0, stream, p1, tmpA, 128);
  hipLaunchKernelGGL(finalize2, dim3(1), dim3(256), 0, stream, tmpA, g1, b1, ssbuf + 256, 64);

  hipLaunchKernelGGL(gemm_max, dim3(2048), dim3(256), 0, stream,
                     y1, Wb + 10240, ssbuf + 256, gm, p2);
  hipLaunchKernelGGL(reduce1, dim3(64), dim3(256), 0, stream, p2, tmpA, 256);
  hipLaunchKernelGGL(finalize2, dim3(1), dim3(256), 0, stream, tmpA, g2, b2, ssbuf + 512, 128);

  hipLaunchKernelGGL(final_out, dim3(1024), dim3(256), 0, stream, gm, ssbuf + 512, out);
}

// Round 8
// 203.289 us; speedup vs baseline: 1.2604x; 1.2604x over previous
//
#include <hip/hip_runtime.h>
#include <cstdint>

typedef unsigned short u16;
typedef unsigned int   u32;
typedef __attribute__((ext_vector_type(8))) short  short8;
typedef __attribute__((ext_vector_type(4))) float  floatx4;

#define NPTS 524288   // B*N2*K

__device__ __forceinline__ float b2f(u16 h) { return __uint_as_float(((u32)h) << 16); }
__device__ __forceinline__ u16 f2b(float f) {
  u32 u = __float_as_uint(f);
  return (u16)((u + 0x7FFFu + ((u >> 16) & 1u)) >> 16);
}
__device__ __forceinline__ u32 pk_bf16(float lo, float hi) {
  return (u32)f2b(lo) | ((u32)f2b(hi) << 16);
}
__device__ __forceinline__ short8 ld_frag8(const u16* p) {
  union { uint4 q; short8 s; } x;
  x.q = *(const uint4*)p;
  return x.s;
}
// barrier that drains ONLY LDS ops — global loads/stores stay in flight
__device__ __forceinline__ void bar_lds() {
  asm volatile("s_waitcnt lgkmcnt(0)\n\ts_barrier" ::: "memory");
}

// ---- combined prep: featT transpose + xyzT transpose + W->bf16 padded ----
// Wb layout (u16): W0 64 x pitch104 @0 (cols 67..103 zero) ; W1 64 x pitch72 @6656 ; W2 128 x pitch72 @11264
__global__ __launch_bounds__(256) void prep_all(const float* __restrict__ inf,
                                                const float* __restrict__ ixyz,
                                                const float* __restrict__ W0,
                                                const float* __restrict__ W1,
                                                const float* __restrict__ W2,
                                                u16* __restrict__ featT,
                                                float4* __restrict__ xyzT,
                                                u16* __restrict__ Wb) {
  __shared__ float tile[32 * 33];
  const int bk = blockIdx.x, t = threadIdx.x;
  if (bk < 4096) {          // in_feature [b][c][n] f32 -> featT [b][n][c] bf16
    int b = bk >> 8, rem = bk & 255, cc = rem >> 7, nc = rem & 127;
    #pragma unroll
    for (int i = 0; i < 4; ++i) {
      int flat = t + i * 256;
      int cl = flat >> 5, nl = flat & 31;
      tile[cl * 33 + nl] = inf[(size_t)((b * 64) + cc * 32 + cl) * 4096 + nc * 32 + nl];
    }
    __syncthreads();
    #pragma unroll
    for (int i = 0; i < 4; ++i) {
      int flat = t + i * 256;
      int nl = flat >> 5, cl = flat & 31;
      featT[(size_t)((b << 12) + nc * 32 + nl) * 64 + cc * 32 + cl] = f2b(tile[cl * 33 + nl]);
    }
  } else if (bk < 4352) {   // in_xyz [b][3][n] -> xyzT [b][n][float4]
    int g = (bk - 4096) * 256 + t;
    int b = g >> 12, n = g & 4095;
    const float* p = ixyz + (size_t)b * 12288;
    xyzT[g] = make_float4(p[n], p[4096 + n], p[8192 + n], 0.f);
  } else {                  // weights: 20480 u16 over 80 blocks
    int s = (bk - 4352) * 256 + t;
    u16 v = 0;
    if (s < 6656)       { int o = s / 104, c = s % 104; if (c < 67) v = f2b(W0[o * 67 + c]); }
    else if (s < 11264) { int q = s - 6656;  int o = q / 72, c = q % 72; if (c < 64) v = f2b(W1[o * 64 + c]); }
    else                { int q = s - 11264; int o = q / 72, c = q % 72; if (c < 64) v = f2b(W2[o * 64 + c]); }
    Wb[s] = v;
  }
}

// ---- main fused layer: 256 rows/block, double-buffered LDS, 2-deep pipeline ----
template<int KSTEPS, int OCH, bool GATHER, bool MAXOUT>
__global__ __launch_bounds__(256, 4) void gemm_layer(
    const u16* __restrict__ xsrc, const float4* __restrict__ xyzT,
    const float* __restrict__ oxyz, const int* __restrict__ nbr,
    const u16* __restrict__ Wb, const float* __restrict__ ssin,
    u16* __restrict__ yout, u32* __restrict__ gm,
    float* __restrict__ partial) {
  constexpr int PITCH = KSTEPS * 32 + 8;   // 104 / 72: <=2-way LDS aliasing
  __shared__ __align__(16) u16 wsh[OCH * PITCH];
  __shared__ __align__(16) u16 xs[2][64 * PITCH];
  __shared__ float red[512];
  __shared__ float ss[GATHER ? 4 : 128];

  const int t = threadIdx.x, blk = blockIdx.x;
  const int lane = t & 63, wv = t >> 6, lr = lane & 15, quad = lane >> 4;
  const int m = t >> 2, s4 = t & 3;
  const int P0 = blk * 256;
  const int b = blk >> 7;

  { // W -> LDS (bf16, same pitch)
    const u32* src = (const u32*)Wb;
    u32* dst = (u32*)wsh;
    constexpr int NW = OCH * PITCH / 2;
    #pragma unroll
    for (int i = 0; i < NW / 256; ++i) dst[t + i * 256] = src[t + i * 256];
  }
  if constexpr (!GATHER) {
    if (t < 128) ss[t] = ssin[t];
  }
  if constexpr (GATHER) {   // zero-pad x cols 67..103 in BOTH buffers (written once)
    #pragma unroll
    for (int bu = 0; bu < 2; ++bu) {
      if (s4 == 1) {
        u16* xr = xs[bu] + m * PITCH;
        xr[67] = 0;
        #pragma unroll
        for (int j = 0; j < 9; ++j) *(uint2*)(xr + 68 + j * 4) = make_uint2(0u, 0u);
      }
    }
  }
  if constexpr (!GATHER) __syncthreads();   // ss visible before commit uses it

  int idx4[4];
  if constexpr (GATHER) {
    #pragma unroll
    for (int sub = 0; sub < 4; ++sub) idx4[sub] = nbr[P0 + sub * 64 + m];
  }

  uint4 f0, f1;
  float DX = 0.f, DY = 0.f, DZ = 0.f;

  auto issue = [&](int sub) {   // global -> regs (stage)
    const int P = P0 + sub * 64 + m;
    if constexpr (GATHER) {
      const int id = idx4[sub];
      const u16* row = xsrc + ((size_t)((b << 12) + id)) * 64;
      f0 = *(const uint4*)(row + s4 * 16);
      f1 = *(const uint4*)(row + s4 * 16 + 8);
      if (s4 == 0) {
        const int n2 = (P & 32767) >> 5;
        float4 p = xyzT[(b << 12) + id];
        DX = p.x - oxyz[(b * 3 + 0) * 1024 + n2];
        DY = p.y - oxyz[(b * 3 + 1) * 1024 + n2];
        DZ = p.z - oxyz[(b * 3 + 2) * 1024 + n2];
      }
    } else {
      const u16* row = xsrc + ((size_t)P << 6);
      f0 = *(const uint4*)(row + s4 * 16);
      f1 = *(const uint4*)(row + s4 * 16 + 8);
    }
  };

  auto commit = [&](int bu) {   // regs -> LDS (BN+ReLU repack for !GATHER)
    u16* xrow = xs[bu] + m * PITCH + s4 * 16;
    if constexpr (GATHER) {
      *(uint4*)(xrow + 0) = f0;
      *(uint4*)(xrow + 8) = f1;
      if (s4 == 0) {
        u16* xr = xs[bu] + m * PITCH;
        xr[64] = f2b(DX); xr[65] = f2b(DY); xr[66] = f2b(DZ);
      }
    } else {
      u32 w[8] = { f0.x, f0.y, f0.z, f0.w, f1.x, f1.y, f1.z, f1.w };
      u32 o[8];
      #pragma unroll
      for (int i = 0; i < 8; ++i) {
        const int c = s4 * 16 + i * 2;
        float lo = fmaxf(b2f((u16)(w[i] & 0xffffu)) * ss[c]     + ss[64 + c],     0.f);
        float hi = fmaxf(b2f((u16)(w[i] >> 16))     * ss[c + 1] + ss[64 + c + 1], 0.f);
        o[i] = pk_bf16(lo, hi);
      }
      *(uint4*)(xrow + 0) = make_uint4(o[0], o[1], o[2], o[3]);
      *(uint4*)(xrow + 8) = make_uint4(o[4], o[5], o[6], o[7]);
    }
  };

  issue(0); commit(0);
  issue(1);
  __syncthreads();   // buf0 (+pads) visible

  float s1[4] = {0.f, 0.f, 0.f, 0.f}, s2[4] = {0.f, 0.f, 0.f, 0.f};
  u32* yo = (u32*)yout;
  const int rg = wv >> 1, cg = wv & 1;   // MAXOUT wave mapping

  for (int sub = 0; sub < 4; ++sub) {
    const int cur = sub & 1;
    if (sub < 3) commit(cur ^ 1);   // prev-iter barrier guarantees buf free
    if (sub < 2) issue(sub + 2);    // loads stay in flight across bar_lds

    if constexpr (!MAXOUT) {
      const u16* ap = xs[cur] + (wv * 16 + lr) * PITCH + quad * 8;
      const u16* bp = wsh + lr * PITCH + quad * 8;
      floatx4 acc[4];
      #pragma unroll
      for (int nt = 0; nt < 4; ++nt) acc[nt] = (floatx4){0.f, 0.f, 0.f, 0.f};
      #pragma unroll
      for (int ks = 0; ks < KSTEPS; ++ks) {
        short8 av = ld_frag8(ap + ks * 32);
        #pragma unroll
        for (int nt = 0; nt < 4; ++nt) {
          short8 bv = ld_frag8(bp + nt * 16 * PITCH + ks * 32);
          acc[nt] = __builtin_amdgcn_mfma_f32_16x16x32_bf16(av, bv, acc[nt], 0, 0, 0);
        }
      }
      const int R0 = P0 + sub * 64 + wv * 16 + quad * 4;
      #pragma unroll
      for (int nt = 0; nt < 4; ++nt) {
        #pragma unroll
        for (int r = 0; r < 4; ++r) {
          float v = acc[nt][r];
          s1[nt] += v; s2[nt] += v * v;
          float vo = __shfl_xor(v, 1);
          if ((lr & 1) == 0)
            yo[(size_t)(R0 + r) * 32 + nt * 8 + (lr >> 1)] = pk_bf16(v, vo);
        }
      }
    } else {
      // wave = 32 rows (rg) x 64 chans (cg): max-group fully in-wave
      const u16* bp = wsh + (cg * 64 + lr) * PITCH + quad * 8;
      short8 av[2][KSTEPS];
      #pragma unroll
      for (int h = 0; h < 2; ++h)
        #pragma unroll
        for (int ks = 0; ks < KSTEPS; ++ks)
          av[h][ks] = ld_frag8(xs[cur] + (rg * 32 + h * 16 + lr) * PITCH + quad * 8 + ks * 32);
      floatx4 acc[2][4];
      #pragma unroll
      for (int h = 0; h < 2; ++h)
        #pragma unroll
        for (int nt = 0; nt < 4; ++nt) acc[h][nt] = (floatx4){0.f, 0.f, 0.f, 0.f};
      #pragma unroll
      for (int ks = 0; ks < KSTEPS; ++ks)
        #pragma unroll
        for (int nt = 0; nt < 4; ++nt) {
          short8 bv = ld_frag8(bp + nt * 16 * PITCH + ks * 32);
          #pragma unroll
          for (int h = 0; h < 2; ++h)
            acc[h][nt] = __builtin_amdgcn_mfma_f32_16x16x32_bf16(av[h][ks], bv, acc[h][nt], 0, 0, 0);
        }
      float mx[4], mn[4];
      #pragma unroll
      for (int nt = 0; nt < 4; ++nt) {
        mx[nt] = -INFINITY; mn[nt] = INFINITY;
        #pragma unroll
        for (int h = 0; h < 2; ++h)
          #pragma unroll
          for (int r = 0; r < 4; ++r) {
            float v = acc[h][nt][r];
            s1[nt] += v; s2[nt] += v * v;
            mx[nt] = fmaxf(mx[nt], v); mn[nt] = fminf(mn[nt], v);
          }
        mx[nt] = fmaxf(mx[nt], __shfl_xor(mx[nt], 16));
        mx[nt] = fmaxf(mx[nt], __shfl_xor(mx[nt], 32));
        mn[nt] = fminf(mn[nt], __shfl_xor(mn[nt], 16));
        mn[nt] = fminf(mn[nt], __shfl_xor(mn[nt], 32));
      }
      if (lane < 16) {
        const int grp = blk * 8 + sub * 2 + rg;   // b*1024 + n2
        #pragma unroll
        for (int nt = 0; nt < 4; ++nt)
          gm[(size_t)grp * 128 + cg * 64 + nt * 16 + lr] = pk_bf16(mx[nt], mn[nt]);
      }
    }
    if (sub < 3) bar_lds();   // LDS-only barrier: vmem stays in flight
  }

  // block stats: shuffle over quads, LDS over waves, single barrier
  #pragma unroll
  for (int nt = 0; nt < 4; ++nt) {
    s1[nt] += __shfl_xor(s1[nt], 16); s1[nt] += __shfl_xor(s1[nt], 32);
    s2[nt] += __shfl_xor(s2[nt], 16); s2[nt] += __shfl_xor(s2[nt], 32);
  }
  if (lane < 16) {
    #pragma unroll
    for (int nt = 0; nt < 4; ++nt) {
      red[wv * 64 + nt * 16 + lr] = s1[nt];
      red[256 + wv * 64 + nt * 16 + lr] = s2[nt];
    }
  }
  __syncthreads();
  if constexpr (!MAXOUT) {
    if (t < 64) {
      partial[(size_t)blk * 128 + t] = red[t] + red[64 + t] + red[128 + t] + red[192 + t];
    } else if (t < 128) {
      int c = t - 64;
      partial[(size_t)blk * 128 + t] = red[256 + c] + red[320 + c] + red[384 + c] + red[448 + c];
    }
  } else {
    // chans 0..63 on waves {0,2}; 64..127 on waves {1,3}
    if (t < 128) {
      int half = t >> 6, i = t & 63;
      partial[(size_t)blk * 256 + t] = red[half * 64 + i] + red[(half + 2) * 64 + i];
    } else {
      int c = t - 128, half = c >> 6, i = c & 63;
      partial[(size_t)blk * 256 + t] = red[256 + half * 64 + i] + red[256 + (half + 2) * 64 + i];
    }
  }
}

// ---- stats tree: 2048 x cols -> 64 x cols -> scale/shift ----
__global__ __launch_bounds__(256) void reduce1(const float* __restrict__ partial,
                                               float* __restrict__ tmp, int cols) {
  int c = threadIdx.x;
  if (c >= cols) return;
  int r0 = blockIdx.x * 32;
  float s = 0.f;
  for (int r = 0; r < 32; ++r) s += partial[(size_t)(r0 + r) * cols + c];
  tmp[blockIdx.x * cols + c] = s;
}

__global__ __launch_bounds__(256) void finalize2(const float* __restrict__ tmp,
                                                 const float* __restrict__ gam,
                                                 const float* __restrict__ bet,
                                                 float* __restrict__ ssout, int och) {
  __shared__ float l[256];
  int t = threadIdx.x, cols = 2 * och;
  if (t < cols) {
    float s = 0.f;
    for (int r = 0; r < 64; ++r) s += tmp[r * cols + t];
    l[t] = s;
  }
  __syncthreads();
  if (t < och) {
    const float invN = 1.f / (float)NPTS;
    float mean = l[t] * invN;
    float var  = fmaxf(l[och + t] * invN - mean * mean, 0.f);
    float scale = gam[t] * rsqrtf(var + 1e-5f);
    ssout[t] = scale;
    ssout[och + t] = bet[t] - mean * scale;
  }
}

// ---- final: BN2 + relu on packed max/min, transpose to [b][c][n2] ----
__global__ __launch_bounds__(256) void final_out(const u32* __restrict__ gm,
                                                 const float* __restrict__ ss2,
                                                 float* __restrict__ out) {
  __shared__ float tile[64 * 33];
  int blk = blockIdx.x;                 // 1024 = 16 * 4 * 16
  int b = blk >> 6, rem = blk & 63, cc = rem >> 4, nn = rem & 15;
  int t = threadIdx.x;
  #pragma unroll
  for (int i = 0; i < 8; ++i) {
    int flat = t + i * 256;             // 2048
    int n2l = flat >> 5, cl = flat & 31;
    int c = cc * 32 + cl;
    size_t idx = (size_t)((b << 10) + nn * 64 + n2l) * 128 + c;
    u32 p = gm[idx];
    float mx = b2f((u16)(p & 0xffffu)), mn = b2f((u16)(p >> 16));
    float scv = ss2[c], shv = ss2[128 + c];
    float v = (scv >= 0.f) ? mx : mn;
    tile[n2l * 33 + cl] = fmaxf(scv * v + shv, 0.f);
  }
  __syncthreads();
  #pragma unroll
  for (int i = 0; i < 8; ++i) {
    int flat = t + i * 256;
    int cl = flat >> 6, n2l = flat & 63;
    out[(size_t)((b * 128) + cc * 32 + cl) * 1024 + nn * 64 + n2l] = tile[n2l * 33 + cl];
  }
}

extern "C" void kernel_launch(void* const* d_in, const int* in_sizes, int n_in,
                              void* d_out, int out_size, void* d_ws, size_t ws_size,
                              hipStream_t stream) {
  const float* in_xyz  = (const float*)d_in[0];
  const float* out_xyz = (const float*)d_in[1];
  const float* in_feat = (const float*)d_in[2];
  const int*   nbr     = (const int*)d_in[3];
  const float* W0 = (const float*)d_in[4];
  const float* g0 = (const float*)d_in[5];
  const float* b0 = (const float*)d_in[6];
  const float* W1 = (const float*)d_in[7];
  const float* g1 = (const float*)d_in[8];
  const float* b1 = (const float*)d_in[9];
  const float* W2 = (const float*)d_in[10];
  const float* g2 = (const float*)d_in[11];
  const float* b2 = (const float*)d_in[12];
  float* out = (float*)d_out;

  char* ws = (char*)d_ws;
  float*  ssbuf = (float*)(ws + 0);            // 768 f32
  u16*    Wb    = (u16*)(ws + 4096);           // 20480 u16
  float*  tmpA  = (float*)(ws + 65536);        // 64*256 f32
  u16*    featT = (u16*)(ws + 262144);         // 8 MiB
  float4* xyzT  = (float4*)(ws + 8650752);     // 1 MiB
  u16*    y0    = (u16*)(ws + 9699328);        // 64 MiB
  u16*    y1    = (u16*)(ws + 76808192);       // 64 MiB (end 143,917,056)
  // aliased into dead regions:
  float*  p0    = (float*)(ws + 76808192);     // y1 area; consumed before y1 written
  float*  p1    = (float*)(ws + 262144);       // featT area; featT dead after L0
  u32*    gm    = (u32*)(ws + 9699328);        // y0 area; y0 dead after L1 (8 MiB packed)
  float*  p2    = (float*)(ws + 9699328 + 8388608);          // 2 MiB

  hipLaunchKernelGGL(prep_all, dim3(4432), dim3(256), 0, stream,
                     in_feat, in_xyz, W0, W1, W2, featT, xyzT, Wb);

  hipLaunchKernelGGL((gemm_layer<3, 64, true, false>), dim3(2048), dim3(256), 0, stream,
                     featT, xyzT, out_xyz, nbr, Wb, nullptr, y0, nullptr, p0);
  hipLaunchKernelGGL(reduce1, dim3(64), dim3(256), 0, stream, p0, tmpA, 128);
  hipLaunchKernelGGL(finalize2, dim3(1), dim3(256), 0, stream, tmpA, g0, b0, ssbuf, 64);

  hipLaunchKernelGGL((gemm_layer<2, 64, false, false>), dim3(2048), dim3(256), 0, stream,
                     y0, nullptr, nullptr, nullptr, Wb + 6656, ssbuf, y1, nullptr, p1);
  hipLaunchKernelGGL(reduce1, dim3(64), dim3(256), 0, stream, p1, tmpA, 128);
  hipLaunchKernelGGL(finalize2, dim3(1), dim3(256), 0, stream, tmpA, g1, b1, ssbuf + 256, 64);

  hipLaunchKernelGGL((gemm_layer<2, 128, false, true>), dim3(2048), dim3(256), 0, stream,
                     y1, nullptr, nullptr, nullptr, Wb + 11264, ssbuf + 256, nullptr, gm, p2);
  hipLaunchKernelGGL(reduce1, dim3(64), dim3(256), 0, stream, p2, tmpA, 256);
  hipLaunchKernelGGL(finalize2, dim3(1), dim3(256), 0, stream, tmpA, g2, b2, ssbuf + 512, 128);

  hipLaunchKernelGGL(final_out, dim3(1024), dim3(256), 0, stream, gm, ssbuf + 512, out);
}